// Round 6
// baseline (330.503 us; speedup 1.0000x reference)
//
#include <hip/hip_runtime.h>
#include <hip/hip_fp16.h>
#include <hip/hip_bf16.h>
#include <stdint.h>

// Problem constants
#define LSEQ 524288   // sequence length
// S = I = C = 64, O = 32

// Phase A (PDA state scan): 4096 chunks x 128 steps, 16-step burn-in
#define KA 128
#define WA 16
#define GA (LSEQ / KA)   // 4096 blocks (64 thr each)

// Phase B (counter scan + readout): 4096 chunks x 128 steps, 2048-step burn-in,
// TWO chunks per wave packed in fp16 pairs -> 2048 waves.
#define KB 128
#define WB 2048
#define GB2 (LSEQ / (2 * KB))   // 2048 blocks (64 thr each)
#define NITER (WB + KB)         // 2176 iterations per wave
#define NBAT (NITER / 64)       // 34 batches
#define NWARM (WB / 64)         // 32 warm batches

// Workspace layout (bytes). Total ~5.27 MB.
#define WS_TP   0u        // uint32[64*2048]: packed T fp16-pairs; tile i, dword (q*64+j)*4+r = (T[2(4q+r),i,j], T[2(4q+r)+1,i,j])
#define WS_IDP  524288u   // uint32[64*64]: (inc_raw[s,i], dec_raw[s,i]) fp16 pair at [i*64+s]
#define WS_WB   540672u   // ushort[32*64]: out_W as fp16, row-major [O][C]
#define WS_INC  544768u   // float[LSEQ]: inc_p
#define WS_DEC  2641920u  // float[LSEQ]: dec_p
#define WS_ST   4739072u  // ushort[64*64*64]: staged softmax(T) fp16, [s][i][j]

typedef __attribute__((ext_vector_type(8))) short short8;
typedef __attribute__((ext_vector_type(8))) _Float16 half8;
typedef __attribute__((ext_vector_type(4))) float f32x4;
typedef __attribute__((ext_vector_type(4))) uint32_t u32x4;

// ---- DPP controls (gfx9/CDNA encodings)
#define DPP_QUAD_XOR1  0xB1   // quad_perm [1,0,3,2]
#define DPP_ROW_ROR1   0x121
#define DPP_ROW_ROR2   0x122
#define DPP_ROW_ROR4   0x124
#define DPP_ROW_ROR8   0x128
#define DPP_WAVE_SHL1  0x130  // dst[i] = src[i+1], lane63 invalid (bound_ctrl -> 0)
#define DPP_WAVE_ROR1  0x13C  // dst[i] = src[(i-1)&63]
#define DPP_BCAST15    0x142
#define DPP_BCAST31    0x143

template<int CTRL, bool BC>
static __device__ __forceinline__ int dpp_mov_i(int x) {
    return __builtin_amdgcn_update_dpp(0, x, CTRL, 0xF, 0xF, BC);
}
template<int CTRL>
static __device__ __forceinline__ float dpp_mov_f(float x) {
    return __int_as_float(__builtin_amdgcn_update_dpp(0, __float_as_int(x), CTRL, 0xF, 0xF, false));
}

static __device__ __forceinline__ uint32_t h2bits(__half2 h) {
    uint32_t u; __builtin_memcpy(&u, &h, 4); return u;
}
static __device__ __forceinline__ __half2 bits2h(uint32_t u) {
    __half2 h; __builtin_memcpy(&h, &u, 4); return h;
}
static __device__ __forceinline__ uint32_t h2add_u(uint32_t a, uint32_t b) {
    return h2bits(__hadd2(bits2h(a), bits2h(b)));
}
static __device__ __forceinline__ float rcp_fast(float x) {
#if __has_builtin(__builtin_amdgcn_rcpf)
    return __builtin_amdgcn_rcpf(x);
#else
    return 1.0f / x;
#endif
}
// lane j: pack (state[j&~1], state[j|1]) low/high via quad_perm xor1 (valid in even lanes)
static __device__ __forceinline__ uint32_t pack_state_pair(float st) {
    uint32_t bits = (uint32_t)__half_as_ushort(__float2half(st));
    uint32_t other = (uint32_t)dpp_mov_i<DPP_QUAD_XOR1, false>((int)bits);
    return bits | (other << 16);
}
// full-wave sum of packed fp16 pair: row_ror allreduce + bcast15/31; broadcast from lane 63
static __device__ __forceinline__ uint32_t wave_red_sum_h2(uint32_t v) {
    v = h2add_u(v, (uint32_t)dpp_mov_i<DPP_ROW_ROR8, false>((int)v));
    v = h2add_u(v, (uint32_t)dpp_mov_i<DPP_ROW_ROR4, false>((int)v));
    v = h2add_u(v, (uint32_t)dpp_mov_i<DPP_ROW_ROR2, false>((int)v));
    v = h2add_u(v, (uint32_t)dpp_mov_i<DPP_ROW_ROR1, false>((int)v));
    v = h2add_u(v, (uint32_t)dpp_mov_i<DPP_BCAST15, false>((int)v));
    v = h2add_u(v, (uint32_t)dpp_mov_i<DPP_BCAST31, false>((int)v));
    return (uint32_t)__builtin_amdgcn_readlane((int)v, 63);
}
// 16-lane-group allreduce via row rotations
static __device__ __forceinline__ float grp16_max(float v) {
    v = fmaxf(v, dpp_mov_f<DPP_ROW_ROR8>(v));
    v = fmaxf(v, dpp_mov_f<DPP_ROW_ROR4>(v));
    v = fmaxf(v, dpp_mov_f<DPP_ROW_ROR2>(v));
    v = fmaxf(v, dpp_mov_f<DPP_ROW_ROR1>(v));
    return v;
}
static __device__ __forceinline__ float grp16_sum(float v) {
    v += dpp_mov_f<DPP_ROW_ROR8>(v);
    v += dpp_mov_f<DPP_ROW_ROR4>(v);
    v += dpp_mov_f<DPP_ROW_ROR2>(v);
    v += dpp_mov_f<DPP_ROW_ROR1>(v);
    return v;
}

// ---------------- prep stage 1: softmax rows (coalesced), IDP, W(fp16) ----------------
__global__ __launch_bounds__(64) void prep_kernel(
    const float* __restrict__ T_raw, const float* __restrict__ inc_raw,
    const float* __restrict__ dec_raw, const float* __restrict__ out_W,
    uint8_t* __restrict__ ws)
{
    int lane = threadIdx.x;
    int bid = blockIdx.x;
    if (bid < 4096) {
        float x = T_raw[bid * 64 + lane];
        float m = x;
        #pragma unroll
        for (int off = 32; off; off >>= 1) m = fmaxf(m, __shfl_xor(m, off));
        float e = __expf(x - m);
        float sum = e;
        #pragma unroll
        for (int off = 32; off; off >>= 1) sum += __shfl_xor(sum, off);
        float v = e / sum;
        ((unsigned short*)(ws + WS_ST))[bid * 64 + lane] = __half_as_ushort(__float2half(v));
    } else if (bid < 4160) {
        int i = bid - 4096;           // lane = s
        float iv = inc_raw[lane * 64 + i];
        float dv = dec_raw[lane * 64 + i];
        __half2 p = __floats2half2_rn(iv, dv);   // low = inc, high = dec
        ((uint32_t*)(ws + WS_IDP))[i * 64 + lane] = h2bits(p);
    } else {
        unsigned short* wbp = (unsigned short*)(ws + WS_WB);
        #pragma unroll
        for (int r = 0; r < 32; ++r) {
            int idx = r * 64 + lane;
            wbp[idx] = __half_as_ushort(__float2half(out_W[idx]));  // fp16 for mfma_f16
        }
    }
}

// ---------------- prep stage 2: transpose staged -> packed coalesced TP ----------------
__global__ __launch_bounds__(64) void prep2_kernel(uint8_t* __restrict__ ws)
{
    int j = threadIdx.x, i = blockIdx.x;
    const unsigned short* st = (const unsigned short*)(ws + WS_ST);
    uint32_t pk[32];
    #pragma unroll
    for (int s2 = 0; s2 < 32; ++s2) {
        uint32_t lo = st[(2 * s2) * 4096 + i * 64 + j];
        uint32_t hi = st[(2 * s2 + 1) * 4096 + i * 64 + j];
        pk[s2] = lo | (hi << 16);
    }
    u32x4* dst = (u32x4*)(ws + WS_TP) + (size_t)i * 512;
    #pragma unroll
    for (int q = 0; q < 8; ++q) {
        u32x4 v = { pk[4 * q], pk[4 * q + 1], pk[4 * q + 2], pk[4 * q + 3] };
        dst[q * 64 + j] = v;   // lanes consecutive -> coalesced
    }
}

// ---------------- phase A: PDA state scan ----------------
static __device__ __forceinline__ void pda_step(
    int k, int warm, int t0, int tstart, int lane,
    const int* __restrict__ seq,
    const u32x4* __restrict__ Tp, const uint32_t* __restrict__ IDP,
    u32x4 (&Tcur)[8], u32x4 (&Tnxt)[8],
    uint32_t& idc, int& inpA,
    float& st, uint32_t& pk,
    float& incK, float& decK,
    float* __restrict__ incArr, float* __restrict__ decArr)
{
    int nidx = tstart + k + 2;
    nidx = nidx < (LSEQ - 1) ? nidx : (LSEQ - 1);
    int inpB = (int)__builtin_amdgcn_readfirstlane(seq[nidx]);
    {
        const u32x4* Trow = Tp + (size_t)inpA * 512 + lane;  // uniform base + lane*16B
        #pragma unroll
        for (int q = 0; q < 8; ++q)
            Tnxt[q] = Trow[q * 64];
    }
    uint32_t idn = (IDP + inpA * 64)[lane];

    // inc/dec logits from current (pre-update) state: packed-fp16 DPP allreduce
    __half2 idh = bits2h(idc);
    float ih = __half2float(__low2half(idh));
    float dh = __half2float(__high2half(idh));
    uint32_t prb = h2bits(__floats2half2_rn(st * ih, st * dh));
    uint32_t tot = wave_red_sum_h2(prb);
    float inc_l = __half2float(__ushort_as_half((unsigned short)(tot & 0xFFFFu)));
    float dec_l = __half2float(__ushort_as_half((unsigned short)(tot >> 16)));
    float e0 = __expf(inc_l);
    float e1 = __expf(dec_l);
    float rs = rcp_fast(e0 + e1 + 1.0f);
    float pi = e0 * rs, pd = e1 * rs;

    // state matvec via v_pk_fma_f16: 4 fp16-pair accumulators, 8 terms each
    __half2 a0 = __hmul2(bits2h(Tcur[0][0]),
                         bits2h((uint32_t)__builtin_amdgcn_readlane(pk, 0)));
    __half2 a1 = __hmul2(bits2h(Tcur[2][0]),
                         bits2h((uint32_t)__builtin_amdgcn_readlane(pk, 16)));
    __half2 a2 = __hmul2(bits2h(Tcur[4][0]),
                         bits2h((uint32_t)__builtin_amdgcn_readlane(pk, 32)));
    __half2 a3 = __hmul2(bits2h(Tcur[6][0]),
                         bits2h((uint32_t)__builtin_amdgcn_readlane(pk, 48)));
    #pragma unroll
    for (int s2 = 1; s2 < 8; ++s2) {
        a0 = __hfma2(bits2h(Tcur[s2 >> 2][s2 & 3]),
                     bits2h((uint32_t)__builtin_amdgcn_readlane(pk, 2 * s2)), a0);
        a1 = __hfma2(bits2h(Tcur[(s2 + 8) >> 2][s2 & 3]),
                     bits2h((uint32_t)__builtin_amdgcn_readlane(pk, 2 * (s2 + 8))), a1);
        a2 = __hfma2(bits2h(Tcur[(s2 + 16) >> 2][s2 & 3]),
                     bits2h((uint32_t)__builtin_amdgcn_readlane(pk, 2 * (s2 + 16))), a2);
        a3 = __hfma2(bits2h(Tcur[(s2 + 24) >> 2][s2 & 3]),
                     bits2h((uint32_t)__builtin_amdgcn_readlane(pk, 2 * (s2 + 24))), a3);
    }
    __half2 s01 = __hadd2(a0, a1), s23 = __hadd2(a2, a3);
    __half2 sall = __hadd2(s01, s23);
    float ns = __low2float(sall) + __high2float(sall);

    if (k >= warm) {
        int loc = k - warm;
        int sl = loc & 63;
        if (lane == sl) { incK = pi; decK = pd; }
        if (sl == 63) {
            int base = t0 + loc - 63;
            incArr[base + lane] = incK;
            decArr[base + lane] = decK;
        }
    }

    st = ns;
    pk = pack_state_pair(st);
    idc = idn;
    inpA = inpB;
}

__global__ __launch_bounds__(64, 4) void pda_kernel(
    const int* __restrict__ seq, const float* __restrict__ initv,
    uint8_t* __restrict__ ws)
{
    int lane = threadIdx.x;
    int g = blockIdx.x;
    const u32x4* Tp = (const u32x4*)(ws + WS_TP);
    const uint32_t* IDP = (const uint32_t*)(ws + WS_IDP);
    float* incArr = (float*)(ws + WS_INC);
    float* decArr = (float*)(ws + WS_DEC);

    int t0 = g * KA;
    int warm = (g == 0) ? 0 : WA;
    int tstart = t0 - warm;
    int nsteps = KA + warm;           // 128 or 144

    float st;
    if (g == 0) {
        float x = initv[lane];
        float m = x;
        #pragma unroll
        for (int off = 32; off; off >>= 1) m = fmaxf(m, __shfl_xor(m, off));
        float e = __expf(x - m);
        float s = e;
        #pragma unroll
        for (int off = 32; off; off >>= 1) s += __shfl_xor(s, off);
        st = e / s;
    } else {
        st = 1.0f / 64.0f;
    }
    uint32_t pk = pack_state_pair(st);

    int inp0 = (int)__builtin_amdgcn_readfirstlane(seq[tstart]);
    int i1 = tstart + 1; i1 = i1 < (LSEQ - 1) ? i1 : (LSEQ - 1);
    int inpA = (int)__builtin_amdgcn_readfirstlane(seq[i1]);

    u32x4 Tc[8], Tn[8];
    {
        const u32x4* Trow = Tp + (size_t)inp0 * 512 + lane;
        #pragma unroll
        for (int q = 0; q < 8; ++q)
            Tc[q] = Trow[q * 64];
    }
    uint32_t idc = (IDP + inp0 * 64)[lane];

    float incK = 0.f, decK = 0.f;

    for (int k = 0; k < nsteps; k += 2) {
        pda_step(k,     warm, t0, tstart, lane, seq, Tp, IDP, Tc, Tn,
                 idc, inpA, st, pk, incK, decK, incArr, decArr);
        pda_step(k + 1, warm, t0, tstart, lane, seq, Tp, IDP, Tn, Tc,
                 idc, inpA, st, pk, incK, decK, incArr, decArr);
    }
}

// ---------------- phase B: TWO counter chunks per wave, packed fp16 ----------------
// dist dword = (fp16 chunkA, fp16 chunkB); DPP shifts move both halves together.
// Chunk A = 2g (times [2g*KB, 2g*KB+KB)), chunk B = 2g+1 (A's window + KB).
// Iteration k: A at t = tau0+k, B at t = tau0+KB+k; t<0 -> zero coefficients
// (dist' == dist exactly), so one-hot init replays exactly from t=0.
__global__ __launch_bounds__(64) void counter_kernel(
    const float* __restrict__ out_b, float* __restrict__ out,
    uint8_t* __restrict__ ws)
{
    __shared__ uint32_t stage[64 * 68];   // 64 rows x 64 pair-dwords, stride 68 (272B, 16B-aligned)
    int lane = threadIdx.x;
    int g = blockIdx.x;
    const float* __restrict__ incArr = (const float*)(ws + WS_INC);
    const float* __restrict__ decArr = (const float*)(ws + WS_DEC);
    const _Float16* wbph = (const _Float16*)(ws + WS_WB);

    int tau0 = 2 * g * KB - WB;

    float i0 = (tau0 <= 0) ? (lane == 0 ? 1.f : 0.f) : (1.f / 64.f);
    float i1v = (tau0 + KB <= 0) ? (lane == 0 ? 1.f : 0.f) : (1.f / 64.f);
    __half2 dist = __floats2half2_rn(i0, i1v);
    float mv = (lane == 0) ? 0.f : -1.f;
    __half2 m1n = __floats2half2_rn(mv, mv);

    int q = lane >> 4, c16 = lane & 15;
    // W frags (fp16): lane holds W[n = nt*16 + c16][k = kb*32 + q*8 + j]
    half8 wf00 = *(const half8*)(wbph + c16 * 64 + q * 8);
    half8 wf10 = *(const half8*)(wbph + c16 * 64 + 32 + q * 8);
    half8 wf01 = *(const half8*)(wbph + (16 + c16) * 64 + q * 8);
    half8 wf11 = *(const half8*)(wbph + (16 + c16) * 64 + 32 + q * 8);
    float b0 = out_b[c16], b1 = out_b[16 + c16];

    __half2 vi, vd, viN, vdN;
    {   // batch 0 (possibly fully padded)
        int tb = tau0;
        float a0 = 0.f, d0 = 0.f, a1 = 0.f, d1 = 0.f;
        if (tb >= 0)      { a0 = incArr[tb + lane];      d0 = decArr[tb + lane]; }
        if (tb + KB >= 0) { a1 = incArr[tb + KB + lane]; d1 = decArr[tb + KB + lane]; }
        vi = __floats2half2_rn(a0, a1);
        vd = __floats2half2_rn(d0, d1);
    }

#define CLOADP(B, VI, VD) { \
        int tb = tau0 + (B) * 64; \
        float a0 = 0.f, d0 = 0.f, a1 = 0.f, d1 = 0.f; \
        if (tb >= 0)      { a0 = incArr[tb + lane];      d0 = decArr[tb + lane]; } \
        if (tb + KB >= 0) { a1 = incArr[tb + KB + lane]; d1 = decArr[tb + KB + lane]; } \
        VI = __floats2half2_rn(a0, a1); \
        VD = __floats2half2_rn(d0, d1); }

#define CSTEP(J) { \
        int db = (int)h2bits(dist); \
        __half2 up = bits2h((uint32_t)dpp_mov_i<DPP_WAVE_ROR1, false>(db)); \
        __half2 dn = bits2h((uint32_t)dpp_mov_i<DPP_WAVE_SHL1, true>(db)); \
        __half2 inc = bits2h((uint32_t)__builtin_amdgcn_readlane((int)h2bits(vi), (J))); \
        __half2 dec = bits2h((uint32_t)__builtin_amdgcn_readlane((int)h2bits(vd), (J))); \
        __half2 t2 = __hfma2(m1n, dist, dn); \
        __half2 s1 = __hsub2(up, dist); \
        __half2 s2 = __hfma2(inc, s1, dist); \
        dist = __hfma2(dec, t2, s2); }

    // ---- warm: 32 batches of 64 iterations, double-buffered prob loads ----
    for (int b = 0; b < NWARM; ++b) {
        CLOADP(b + 1, viN, vdN);
        #pragma unroll
        for (int j = 0; j < 64; ++j) CSTEP(j);
        vi = viN; vd = vdN;
    }

    // ---- emit: 2 batches; stage pre-update pair dwords, MFMA epilogue per batch ----
    int rbase = 2 * g * KB;
    for (int e = 0; e < 2; ++e) {
        if (e == 0) { CLOADP(NWARM + 1, viN, vdN); }
        #pragma unroll
        for (int j = 0; j < 64; ++j) {
            stage[j * 68 + lane] = h2bits(dist);   // PRE-update dist pair
            CSTEP(j);
        }
        int rbA = rbase + e * 64;
        #pragma unroll
        for (int t = 0; t < 4; ++t) {
            const uint32_t* sp = stage + (t * 16 + c16) * 68;
            uint32_t dw[16];
            *(u32x4*)(dw)      = *(const u32x4*)(sp + q * 8);
            *(u32x4*)(dw + 4)  = *(const u32x4*)(sp + q * 8 + 4);
            *(u32x4*)(dw + 8)  = *(const u32x4*)(sp + 32 + q * 8);
            *(u32x4*)(dw + 12) = *(const u32x4*)(sp + 32 + q * 8 + 4);
            uint32_t fA0[4], fB0[4], fA1[4], fB1[4];
            #pragma unroll
            for (int i = 0; i < 4; ++i) {
                fA0[i] = __builtin_amdgcn_perm(dw[2 * i + 1], dw[2 * i], 0x05040100u);
                fB0[i] = __builtin_amdgcn_perm(dw[2 * i + 1], dw[2 * i], 0x07060302u);
                fA1[i] = __builtin_amdgcn_perm(dw[8 + 2 * i + 1], dw[8 + 2 * i], 0x05040100u);
                fB1[i] = __builtin_amdgcn_perm(dw[8 + 2 * i + 1], dw[8 + 2 * i], 0x07060302u);
            }
            half8 aA0, aA1, aB0, aB1;
            __builtin_memcpy(&aA0, fA0, 16);
            __builtin_memcpy(&aA1, fA1, 16);
            __builtin_memcpy(&aB0, fB0, 16);
            __builtin_memcpy(&aB1, fB1, 16);
            f32x4 dA0 = {0.f,0.f,0.f,0.f}, dA1 = {0.f,0.f,0.f,0.f};
            f32x4 dB0 = {0.f,0.f,0.f,0.f}, dB1 = {0.f,0.f,0.f,0.f};
            dA0 = __builtin_amdgcn_mfma_f32_16x16x32_f16(aA0, wf00, dA0, 0, 0, 0);
            dA0 = __builtin_amdgcn_mfma_f32_16x16x32_f16(aA1, wf10, dA0, 0, 0, 0);
            dA1 = __builtin_amdgcn_mfma_f32_16x16x32_f16(aA0, wf01, dA1, 0, 0, 0);
            dA1 = __builtin_amdgcn_mfma_f32_16x16x32_f16(aA1, wf11, dA1, 0, 0, 0);
            dB0 = __builtin_amdgcn_mfma_f32_16x16x32_f16(aB0, wf00, dB0, 0, 0, 0);
            dB0 = __builtin_amdgcn_mfma_f32_16x16x32_f16(aB1, wf10, dB0, 0, 0, 0);
            dB1 = __builtin_amdgcn_mfma_f32_16x16x32_f16(aB0, wf01, dB1, 0, 0, 0);
            dB1 = __builtin_amdgcn_mfma_f32_16x16x32_f16(aB1, wf11, dB1, 0, 0, 0);
            int rowA = rbA + t * 16 + q * 4;
            #pragma unroll
            for (int r = 0; r < 4; ++r) {
                // chunk A
                float l0 = dA0[r] + b0, l1 = dA1[r] + b1;
                float mm = grp16_max(fmaxf(l0, l1));
                float e0 = __expf(l0 - mm), e1 = __expf(l1 - mm);
                float ssum = grp16_sum(e0 + e1);
                float rinv = rcp_fast(ssum);
                out[(rowA + r) * 32 + c16]      = e0 * rinv;
                out[(rowA + r) * 32 + 16 + c16] = e1 * rinv;
                // chunk B (rows + KB)
                float l0b = dB0[r] + b0, l1b = dB1[r] + b1;
                float mmb = grp16_max(fmaxf(l0b, l1b));
                float e0b = __expf(l0b - mmb), e1b = __expf(l1b - mmb);
                float ssb = grp16_sum(e0b + e1b);
                float rib = rcp_fast(ssb);
                out[(rowA + KB + r) * 32 + c16]      = e0b * rib;
                out[(rowA + KB + r) * 32 + 16 + c16] = e1b * rib;
            }
        }
        vi = viN; vd = vdN;
    }
#undef CSTEP
#undef CLOADP
}

extern "C" void kernel_launch(void* const* d_in, const int* in_sizes, int n_in,
                              void* d_out, int out_size, void* d_ws, size_t ws_size,
                              hipStream_t stream) {
    const int*   seq     = (const int*)d_in[0];
    const float* T_raw   = (const float*)d_in[1];
    const float* inc_raw = (const float*)d_in[2];
    const float* dec_raw = (const float*)d_in[3];
    const float* out_W   = (const float*)d_in[4];
    const float* out_b   = (const float*)d_in[5];
    const float* initv   = (const float*)d_in[6];
    float* out = (float*)d_out;
    uint8_t* ws = (uint8_t*)d_ws;
    (void)in_sizes; (void)n_in; (void)out_size; (void)ws_size;

    hipLaunchKernelGGL(prep_kernel, dim3(4161), dim3(64), 0, stream,
                       T_raw, inc_raw, dec_raw, out_W, ws);
    hipLaunchKernelGGL(prep2_kernel, dim3(64), dim3(64), 0, stream, ws);
    hipLaunchKernelGGL(pda_kernel, dim3(GA), dim3(64), 0, stream, seq, initv, ws);
    hipLaunchKernelGGL(counter_kernel, dim3(GB2), dim3(64), 0, stream, out_b, out, ws);
}